// Round 1
// baseline (575.346 us; speedup 1.0000x reference)
//
#include <hip/hip_runtime.h>
#include <hip/hip_bf16.h>
#include <stdint.h>

#define S 8192
#define D 512
#define SCALE 0.044194173824159216f  // 1/sqrt(512)
#define KSPLIT 8

typedef __attribute__((ext_vector_type(8))) short short8;
typedef __attribute__((ext_vector_type(4))) float f32x4;

__device__ inline unsigned short f32_to_bf16(float f) {
    union { float f; uint32_t u; } v; v.f = f;
    uint32_t u = v.u;
    uint32_t r = (u + 0x7FFFu + ((u >> 16) & 1u)) >> 16;
    return (unsigned short)r;
}

__device__ inline uint2 pack4(float4 v) {
    uint2 p;
    p.x = (uint32_t)f32_to_bf16(v.x) | ((uint32_t)f32_to_bf16(v.y) << 16);
    p.y = (uint32_t)f32_to_bf16(v.z) | ((uint32_t)f32_to_bf16(v.w) << 16);
    return p;
}

// ---------------- convert fp32 inputs to bf16 ----------------
__global__ __launch_bounds__(256) void k_convert(
    const float* __restrict__ x, const float* __restrict__ Wq,
    const float* __restrict__ Wk, const float* __restrict__ Wv,
    short* __restrict__ xb, short* __restrict__ Wb) {
    size_t i4 = (size_t)blockIdx.x * 256 + threadIdx.x;
    const size_t XN4 = (size_t)S * D / 4;      // 1048576
    if (i4 < XN4) {
        float4 v = reinterpret_cast<const float4*>(x)[i4];
        reinterpret_cast<uint2*>(xb)[i4] = pack4(v);
    } else {
        size_t j4 = i4 - XN4;                   // < 3*D*D/4 = 196608
        size_t w = j4 >> 16;                    // D*D/4 = 65536
        size_t rem = j4 & 65535;
        const float* src = (w == 0) ? Wq : ((w == 1) ? Wk : Wv);
        float4 v = reinterpret_cast<const float4*>(src)[rem];
        reinterpret_cast<uint2*>(Wb)[j4] = pack4(v);
    }
}

// ---------------- shared GEMM pieces ----------------
// stage a 128x32 bf16 tile from row-major src (leading dim ld) into LDS (linear [128][32])
__device__ inline void stage_bf16(const short* __restrict__ src, int ld, short* dst, int t) {
#pragma unroll
    for (int j = 0; j < 2; j++) {
        int c = t + j * 256;          // 512 chunks of 8 shorts
        int r = c >> 2;
        int kc = (c & 3) * 8;
        uint4 v = *reinterpret_cast<const uint4*>(&src[(size_t)r * ld + kc]);
        *reinterpret_cast<uint4*>(&dst[r * 32 + kc]) = v;
    }
}

__device__ inline void mfma_tile(const short* As, const short* Bs,
                                 f32x4 acc[4][4], int wr, int wc, int lane) {
    int rl = lane & 15;
    int kg = lane >> 4;   // 0..3, holds k = kg*8 .. kg*8+7
    short8 a[4], b[4];
#pragma unroll
    for (int m = 0; m < 4; m++)
        a[m] = *reinterpret_cast<const short8*>(&As[(wr * 64 + m * 16 + rl) * 32 + kg * 8]);
#pragma unroll
    for (int n = 0; n < 4; n++)
        b[n] = *reinterpret_cast<const short8*>(&Bs[(wc * 64 + n * 16 + rl) * 32 + kg * 8]);
#pragma unroll
    for (int m = 0; m < 4; m++)
#pragma unroll
        for (int n = 0; n < 4; n++)
            acc[m][n] = __builtin_amdgcn_mfma_f32_16x16x32_bf16(a[m], b[n], acc[m][n], 0, 0, 0);
}

// ---------------- QKV projection: out = xb @ W^T + b, bf16 out ----------------
__global__ __launch_bounds__(256) void k_qkv(
    const short* __restrict__ xb, const short* __restrict__ Wb,
    const float* __restrict__ bq, const float* __restrict__ bk,
    const float* __restrict__ bv, short* __restrict__ QKV) {
    __shared__ short As[128 * 32], Bs[128 * 32];
    int which = blockIdx.z;
    const short* W = Wb + (size_t)which * D * D;
    const float* bias = (which == 0) ? bq : ((which == 1) ? bk : bv);
    short* out = QKV + (size_t)which * S * D;
    int r0 = blockIdx.x * 128, c0 = blockIdx.y * 128;
    int t = threadIdx.x, lane = t & 63, w = t >> 6, wr = w >> 1, wc = w & 1;
    f32x4 acc[4][4];
#pragma unroll
    for (int m = 0; m < 4; m++)
#pragma unroll
        for (int n = 0; n < 4; n++)
#pragma unroll
            for (int j = 0; j < 4; j++) acc[m][n][j] = 0.0f;

    for (int kk = 0; kk < D; kk += 32) {
        __syncthreads();
        stage_bf16(xb + (size_t)r0 * D + kk, D, As, t);
        stage_bf16(W + (size_t)c0 * D + kk, D, Bs, t);
        __syncthreads();
        mfma_tile(As, Bs, acc, wr, wc, lane);
    }
    int rg = lane >> 4, cl = lane & 15;
#pragma unroll
    for (int m = 0; m < 4; m++)
#pragma unroll
        for (int n = 0; n < 4; n++) {
            int col = c0 + wc * 64 + n * 16 + cl;
            float b = bias[col];
#pragma unroll
            for (int j = 0; j < 4; j++) {
                int row = r0 + wr * 64 + m * 16 + rg * 4 + j;
                out[(size_t)row * D + col] = (short)f32_to_bf16(acc[m][n][j] + b);
            }
        }
}

// ---------------- V transpose: Vt[d][s] = V[s][d] ----------------
__global__ __launch_bounds__(256) void k_transpose(const short* __restrict__ V,
                                                   short* __restrict__ Vt) {
    __shared__ short tile[64][65];
    int r0 = blockIdx.x * 64;   // S
    int c0 = blockIdx.y * 64;   // D
    int t = threadIdx.x;
#pragma unroll
    for (int j = 0; j < 16; j++) {
        int idx = t + j * 256;
        int r = idx >> 6, c = idx & 63;
        tile[r][c] = V[(size_t)(r0 + r) * D + c0 + c];
    }
    __syncthreads();
#pragma unroll
    for (int j = 0; j < 16; j++) {
        int idx = t + j * 256;
        int rr = idx >> 6, cc = idx & 63;
        Vt[(size_t)(c0 + rr) * S + r0 + cc] = tile[cc][rr];
    }
}

// ---------------- scores: attn_raw = (Q @ K^T) * scale, causal, raw fp32 ----------------
__global__ __launch_bounds__(256) void k_scores(const short* __restrict__ Qb,
                                                const short* __restrict__ Kb,
                                                float* __restrict__ attn) {
    int bj = blockIdx.x, bi = blockIdx.y;
    int r0 = bi * 128, c0 = bj * 128;
    int t = threadIdx.x;
    if (bj > bi) {  // strictly upper tile: zeros (final attn value)
#pragma unroll
        for (int j = 0; j < 16; j++) {
            int c = t + j * 256;
            int r = c >> 5;
            int c4 = (c & 31) * 4;
            *reinterpret_cast<float4*>(&attn[(size_t)(r0 + r) * S + c0 + c4]) =
                make_float4(0.f, 0.f, 0.f, 0.f);
        }
        return;
    }
    __shared__ short As[128 * 32], Bs[128 * 32];
    int lane = t & 63, w = t >> 6, wr = w >> 1, wc = w & 1;
    f32x4 acc[4][4];
#pragma unroll
    for (int m = 0; m < 4; m++)
#pragma unroll
        for (int n = 0; n < 4; n++)
#pragma unroll
            for (int j = 0; j < 4; j++) acc[m][n][j] = 0.0f;

    for (int kk = 0; kk < D; kk += 32) {
        __syncthreads();
        stage_bf16(Qb + (size_t)r0 * D + kk, D, As, t);
        stage_bf16(Kb + (size_t)c0 * D + kk, D, Bs, t);
        __syncthreads();
        mfma_tile(As, Bs, acc, wr, wc, lane);
    }
    int rg = lane >> 4, cl = lane & 15;
#pragma unroll
    for (int m = 0; m < 4; m++)
#pragma unroll
        for (int n = 0; n < 4; n++) {
            int col = c0 + wc * 64 + n * 16 + cl;
#pragma unroll
            for (int j = 0; j < 4; j++) {
                int row = r0 + wr * 64 + m * 16 + rg * 4 + j;
                float v = acc[m][n][j] * SCALE;
                if (col > row) v = 0.0f;  // only on diagonal tiles
                attn[(size_t)row * S + col] = v;
            }
        }
}

// ---------------- row softmax over valid prefix [0, i] (in place) ----------------
__global__ __launch_bounds__(256) void k_softmax(float* __restrict__ attn) {
    __shared__ float buf[S];
    __shared__ float red[16];
    int i = blockIdx.x;
    int t = threadIdx.x;
    int n = i + 1;
    float m = -__builtin_inff();
    for (int j = t; j < n; j += 256) {
        float v = attn[(size_t)i * S + j];
        buf[j] = v;
        m = fmaxf(m, v);
    }
#pragma unroll
    for (int o = 32; o > 0; o >>= 1) m = fmaxf(m, __shfl_xor(m, o, 64));
    int wid = t >> 6, lane = t & 63;
    if (lane == 0) red[wid] = m;
    __syncthreads();
    if (t == 0) {
        float mm = fmaxf(fmaxf(red[0], red[1]), fmaxf(red[2], red[3]));
        red[8] = mm;
    }
    __syncthreads();
    float M = red[8];
    float s = 0.f;
    for (int j = t; j < n; j += 256) {
        float e = __expf(buf[j] - M);
        buf[j] = e;
        s += e;
    }
#pragma unroll
    for (int o = 32; o > 0; o >>= 1) s += __shfl_xor(s, o, 64);
    __syncthreads();
    if (lane == 0) red[wid] = s;
    __syncthreads();
    if (t == 0) red[9] = 1.0f / (red[0] + red[1] + red[2] + red[3]);
    __syncthreads();
    float inv = red[9];
    for (int j = t; j < n; j += 256) attn[(size_t)i * S + j] = buf[j] * inv;
}

// ---------------- PV: out += attn @ V  (A fp32->bf16 on the fly, K-split + atomics) ----------------
__global__ __launch_bounds__(256) void k_pv(const float* __restrict__ attn,
                                            const short* __restrict__ Vt,
                                            float* __restrict__ out) {
    int bn = blockIdx.x;   // 0..3
    int bi = blockIdx.y;   // 0..63
    int kz = blockIdx.z;   // 0..KSPLIT-1
    int nsteps = (bi + 1) * 4;                       // 32-wide k-steps
    int per = (nsteps + KSPLIT - 1) / KSPLIT;
    int st0 = kz * per, st1 = min(nsteps, st0 + per);
    if (st0 >= st1) return;
    __shared__ short As[128 * 32], Bs[128 * 32];
    int r0 = bi * 128, c0 = bn * 128;
    int t = threadIdx.x, lane = t & 63, w = t >> 6, wr = w >> 1, wc = w & 1;
    f32x4 acc[4][4];
#pragma unroll
    for (int m = 0; m < 4; m++)
#pragma unroll
        for (int n = 0; n < 4; n++)
#pragma unroll
            for (int j = 0; j < 4; j++) acc[m][n][j] = 0.0f;

    for (int st = st0; st < st1; ++st) {
        int kk = st * 32;
        __syncthreads();
        // stage A: 128x32 fp32 -> bf16
#pragma unroll
        for (int j = 0; j < 4; j++) {
            int c = t + j * 256;          // 1024 float4 chunks
            int r = c >> 3;
            int kc = (c & 7) * 4;
            float4 v = *reinterpret_cast<const float4*>(&attn[(size_t)(r0 + r) * S + kk + kc]);
            *reinterpret_cast<uint2*>(&As[r * 32 + kc]) = pack4(v);
        }
        // stage B from Vt (bf16)
#pragma unroll
        for (int j = 0; j < 2; j++) {
            int c = t + j * 256;          // 512 chunks of 8 shorts
            int r = c >> 2;
            int kc = (c & 3) * 8;
            uint4 v = *reinterpret_cast<const uint4*>(&Vt[(size_t)(c0 + r) * S + kk + kc]);
            *reinterpret_cast<uint4*>(&Bs[r * 32 + kc]) = v;
        }
        __syncthreads();
        mfma_tile(As, Bs, acc, wr, wc, lane);
    }
    int rg = lane >> 4, cl = lane & 15;
#pragma unroll
    for (int m = 0; m < 4; m++)
#pragma unroll
        for (int n = 0; n < 4; n++) {
            int col = c0 + wc * 64 + n * 16 + cl;
#pragma unroll
            for (int j = 0; j < 4; j++) {
                int row = r0 + wr * 64 + m * 16 + rg * 4 + j;
                atomicAdd(&out[(size_t)row * D + col], acc[m][n][j]);
            }
        }
}

extern "C" void kernel_launch(void* const* d_in, const int* in_sizes, int n_in,
                              void* d_out, int out_size, void* d_ws, size_t ws_size,
                              hipStream_t stream) {
    const float* x  = (const float*)d_in[0];
    const float* Wq = (const float*)d_in[1];
    const float* bq = (const float*)d_in[2];
    const float* Wk = (const float*)d_in[3];
    const float* bk = (const float*)d_in[4];
    const float* Wv = (const float*)d_in[5];
    const float* bv = (const float*)d_in[6];
    float* out  = (float*)d_out;
    float* attn = out + (size_t)S * D;

    short* xb  = (short*)d_ws;                 // S*D bf16
    short* Wb  = xb + (size_t)S * D;           // 3*D*D bf16
    short* QKV = Wb + (size_t)3 * D * D;       // 3*S*D bf16
    short* Vt  = QKV + (size_t)3 * S * D;      // D*S bf16
    const short* Qb = QKV;
    const short* Kb = QKV + (size_t)S * D;
    const short* Vb = QKV + (size_t)2 * S * D;

    {
        size_t total4 = (size_t)S * D / 4 + (size_t)3 * D * D / 4;  // 1245184
        k_convert<<<dim3((unsigned)(total4 / 256)), 256, 0, stream>>>(x, Wq, Wk, Wv, xb, Wb);
    }
    k_qkv<<<dim3(S / 128, D / 128, 3), 256, 0, stream>>>(xb, Wb, bq, bk, bv, QKV);
    k_transpose<<<dim3(S / 64, D / 64), 256, 0, stream>>>(Vb, Vt);
    k_scores<<<dim3(S / 128, S / 128), 256, 0, stream>>>(Qb, Kb, attn);
    k_softmax<<<dim3(S), 256, 0, stream>>>(attn);
    hipMemsetAsync(d_out, 0, (size_t)S * D * sizeof(float), stream);
    k_pv<<<dim3(D / 128, S / 128, KSPLIT), 256, 0, stream>>>(attn, Vt, out);
}